// Round 4
// baseline (19.646 us; speedup 1.0000x reference)
//
#include <hip/hip_runtime.h>
#include <math.h>

typedef __attribute__((ext_vector_type(8))) short bf16x8;
typedef __attribute__((ext_vector_type(4))) float f32x4;
typedef __attribute__((ext_vector_type(4))) unsigned int u32x4;

#define TPB  256
#define NBLK 256

// d_ws u32-word layout (1 word = 2 bf16, k-pair packed):
//   W1T [128 n][64 w] | W2T [64 n][64 w] | W3T [32 n][32 w]
#define WS_W1 0
#define WS_W2 8192
#define WS_W3 12288

// LDS byte offsets
#define W1T_OFF 0                       // [128 n][272 B]
#define W2T_OFF 34816                   // [64  n][272 B]
#define W3T_OFF 52224                   // [32  n][144 B]
#define SCR_OFF 56832                   // per-wave [16][272 B] scratch
#define SCR_PW  4352
#define SM_BYTES 74240

__device__ __forceinline__ unsigned short f2bf(float a){
  unsigned ua = __float_as_uint(a);
  return (unsigned short)((ua + 0x7FFFu + ((ua>>16)&1u)) >> 16);   // RNE
}
__device__ __forceinline__ unsigned int f2bf_pk(float a, float b){
  return (unsigned int)f2bf(a) | ((unsigned int)f2bf(b) << 16);
}
__device__ __forceinline__ bf16x8 mk_frag(float4 a, float4 ba, float4 b, float4 bb){
  union { bf16x8 v; unsigned int u[4]; } o;
  o.u[0] = f2bf_pk(fmaxf(a.x+ba.x,0.f), fmaxf(a.y+ba.y,0.f));
  o.u[1] = f2bf_pk(fmaxf(a.z+ba.z,0.f), fmaxf(a.w+ba.w,0.f));
  o.u[2] = f2bf_pk(fmaxf(b.x+bb.x,0.f), fmaxf(b.y+bb.y,0.f));
  o.u[3] = f2bf_pk(fmaxf(b.z+bb.z,0.f), fmaxf(b.w+bb.w,0.f));
  return o.v;
}

// ---- kernel A: one-shot weight convert/transpose into d_ws ----
__global__ void __launch_bounds__(256) ncf_convert(
    const float* __restrict__ W1, const float* __restrict__ W2,
    const float* __restrict__ W3, unsigned int* __restrict__ ws)
{
  const int p = blockIdx.x * 256 + threadIdx.x;   // 52*256 = 13312 words
  float f0, f1; int dst;
  if (p < 8192)       { int kp = p >> 7,            n = p & 127;
    f0 = W1[(2*kp)*128 + n]; f1 = W1[(2*kp+1)*128 + n]; dst = WS_W1 + n*64 + kp; }
  else if (p < 12288) { int q = p - 8192,  kp = q >> 6, n = q & 63;
    f0 = W2[(2*kp)*64  + n]; f1 = W2[(2*kp+1)*64  + n]; dst = WS_W2 + n*64 + kp; }
  else                { int q = p - 12288, kp = q >> 5, n = q & 31;
    f0 = W3[(2*kp)*32  + n]; f1 = W3[(2*kp+1)*32  + n]; dst = WS_W3 + n*32 + kp; }
  ws[dst] = f2bf_pk(f0, f1);
}

// ---- kernel B: gather + GMF + MFMA tower ----
__launch_bounds__(TPB, 2)
__global__ void ncf_mfma(
    const int* __restrict__ user, const int* __restrict__ item,
    const float* __restrict__ Wug, const float* __restrict__ bug,
    const float* __restrict__ Wum, const float* __restrict__ bum,
    const float* __restrict__ Wig, const float* __restrict__ big,
    const float* __restrict__ Wim, const float* __restrict__ bim,
    const float* __restrict__ b1, const float* __restrict__ b2,
    const float* __restrict__ b3,
    const float* __restrict__ Wp, const float* __restrict__ bp,
    const unsigned int* __restrict__ ws,
    float* __restrict__ out)
{
  extern __shared__ __align__(16) char sm[];
  const int t    = threadIdx.x;
  const int lane = t & 63;
  const int w    = t >> 6;           // 0..3
  const int r    = lane & 15;
  const int g    = lane >> 4;
  const int gb   = blockIdx.x * 64 + w * 16 + r;

  // ---- issue index + embedding gathers first (longest latency) ----
  const int u  = user[gb];
  const int it = item[gb];
  const float* up = Wum + (size_t)u  * 64;
  const float* ip = Wim + (size_t)it * 64;
  float4 mu0 = *(const float4*)(up + 8*g);
  float4 mu1 = *(const float4*)(up + 8*g + 4);
  float4 mu2 = *(const float4*)(up + 32 + 8*g);
  float4 mu3 = *(const float4*)(up + 32 + 8*g + 4);
  float4 mi0 = *(const float4*)(ip + 8*g);
  float4 mi1 = *(const float4*)(ip + 8*g + 4);
  float4 mi2 = *(const float4*)(ip + 32 + 8*g);
  float4 mi3 = *(const float4*)(ip + 32 + 8*g + 4);

  const float* ugp = Wug + (size_t)u  * 64 + 16*g;
  const float* igp = Wig + (size_t)it * 64 + 16*g;

  // ---- staging: contiguous bf16 chunks from ws -> padded LDS ----
  const u32x4* wsv = (const u32x4*)ws;
  #pragma unroll
  for (int i = 0; i < 8; ++i) {                  // W1: 2048 16B-chunks
    int c = i*TPB + t; int n = c >> 4, sub = c & 15;
    *(u32x4*)(sm + W1T_OFF + n*272 + sub*16) = wsv[c];
  }
  #pragma unroll
  for (int i = 0; i < 4; ++i) {                  // W2: 1024 chunks
    int c = i*TPB + t; int n = c >> 4, sub = c & 15;
    *(u32x4*)(sm + W2T_OFF + n*272 + sub*16) = wsv[2048 + c];
  }
  {                                              // W3: 256 chunks
    int c = t; int n = c >> 3, sub = c & 7;
    *(u32x4*)(sm + W3T_OFF + n*144 + sub*16) = wsv[3072 + c];
  }

  // ---- GMF (f32 exact): this lane's 16 cols ----
  float psum = 0.f;
  #pragma unroll
  for (int c = 0; c < 4; ++c) {
    float4 ga  = *(const float4*)(ugp + 4*c);
    float4 gi  = *(const float4*)(igp + 4*c);
    float4 gba = *(const float4*)(bug + 16*g + 4*c);
    float4 gbb = *(const float4*)(big + 16*g + 4*c);
    float4 wpv = *(const float4*)(Wp  + 16*g + 4*c);
    psum += fmaxf(ga.x+gba.x,0.f) * fmaxf(gi.x+gbb.x,0.f) * wpv.x;
    psum += fmaxf(ga.y+gba.y,0.f) * fmaxf(gi.y+gbb.y,0.f) * wpv.y;
    psum += fmaxf(ga.z+gba.z,0.f) * fmaxf(gi.z+gbb.z,0.f) * wpv.z;
    psum += fmaxf(ga.w+gba.w,0.f) * fmaxf(gi.w+gbb.w,0.f) * wpv.w;
  }

  // ---- layer-1 A fragments straight from the gather ----
  float4 bu0 = *(const float4*)(bum + 8*g);      float4 bu1 = *(const float4*)(bum + 8*g + 4);
  float4 bu2 = *(const float4*)(bum + 32 + 8*g); float4 bu3 = *(const float4*)(bum + 32 + 8*g + 4);
  float4 bi0 = *(const float4*)(bim + 8*g);      float4 bi1 = *(const float4*)(bim + 8*g + 4);
  float4 bi2 = *(const float4*)(bim + 32 + 8*g); float4 bi3 = *(const float4*)(bim + 32 + 8*g + 4);
  bf16x8 afr[4];
  afr[0] = mk_frag(mu0, bu0, mu1, bu1);
  afr[1] = mk_frag(mu2, bu2, mu3, bu3);
  afr[2] = mk_frag(mi0, bi0, mi1, bi1);
  afr[3] = mk_frag(mi2, bi2, mi3, bi3);

  float b1v[8], b2v[4], b3v[2], wp3[2];
  #pragma unroll
  for (int i = 0; i < 8; ++i) b1v[i] = b1[i*16 + r];
  #pragma unroll
  for (int i = 0; i < 4; ++i) b2v[i] = b2[i*16 + r];
  #pragma unroll
  for (int i = 0; i < 2; ++i) { b3v[i] = b3[i*16 + r]; wp3[i] = Wp[64 + i*16 + r]; }
  const float bpv = bp[0];

  __syncthreads();   // weights staged

  char* scr = sm + SCR_OFF + w * SCR_PW;   // wave-private scratch

  // ---- layer 1: [16,128] @ [128,128] ----
  #pragma unroll
  for (int nt = 0; nt < 8; ++nt) {
    f32x4 acc = {b1v[nt], b1v[nt], b1v[nt], b1v[nt]};
    #pragma unroll
    for (int s = 0; s < 4; ++s) {
      bf16x8 bf = *(const bf16x8*)(sm + W1T_OFF + (nt*16 + r)*272 + s*64 + g*16);
      acc = __builtin_amdgcn_mfma_f32_16x16x32_bf16(afr[s], bf, acc, 0, 0, 0);
    }
    #pragma unroll
    for (int q = 0; q < 4; ++q)
      *(unsigned short*)(scr + (4*g + q)*272 + (nt*16 + r)*2) = f2bf(fmaxf(acc[q], 0.f));
  }

  // ---- layer 2: [16,128] @ [128,64] ----
  bf16x8 a2[4];
  #pragma unroll
  for (int s = 0; s < 4; ++s)
    a2[s] = *(const bf16x8*)(scr + r*272 + s*64 + g*16);
  #pragma unroll
  for (int nt = 0; nt < 4; ++nt) {
    f32x4 acc = {b2v[nt], b2v[nt], b2v[nt], b2v[nt]};
    #pragma unroll
    for (int s = 0; s < 4; ++s) {
      bf16x8 bf = *(const bf16x8*)(sm + W2T_OFF + (nt*16 + r)*272 + s*64 + g*16);
      acc = __builtin_amdgcn_mfma_f32_16x16x32_bf16(a2[s], bf, acc, 0, 0, 0);
    }
    #pragma unroll
    for (int q = 0; q < 4; ++q)
      *(unsigned short*)(scr + (4*g + q)*144 + (nt*16 + r)*2) = f2bf(fmaxf(acc[q], 0.f));
  }

  // ---- layer 3: [16,64] @ [64,32] ----
  bf16x8 a3[2];
  #pragma unroll
  for (int s = 0; s < 2; ++s)
    a3[s] = *(const bf16x8*)(scr + r*144 + s*64 + g*16);
  float h3p[4] = {0.f, 0.f, 0.f, 0.f};
  #pragma unroll
  for (int nt = 0; nt < 2; ++nt) {
    f32x4 acc = {b3v[nt], b3v[nt], b3v[nt], b3v[nt]};
    #pragma unroll
    for (int s = 0; s < 2; ++s) {
      bf16x8 bf = *(const bf16x8*)(sm + W3T_OFF + (nt*16 + r)*144 + s*64 + g*16);
      acc = __builtin_amdgcn_mfma_f32_16x16x32_bf16(a3[s], bf, acc, 0, 0, 0);
    }
    #pragma unroll
    for (int q = 0; q < 4; ++q)
      h3p[q] += fmaxf(acc[q], 0.f) * wp3[nt];
  }

  // ---- final reduce in wave-private scratch (f32 [16][20]) ----
  float* scf = (float*)scr;
  #pragma unroll
  for (int q = 0; q < 4; ++q) scf[(4*g + q)*20 + r] = h3p[q];
  scf[r*20 + 16 + g] = psum;
  __builtin_amdgcn_wave_barrier();

  if (lane < 16) {
    const float4* row = (const float4*)(scf + lane*20);
    float x = bpv;
    #pragma unroll
    for (int i = 0; i < 5; ++i) { float4 v = row[i]; x += v.x + v.y + v.z + v.w; }
    out[blockIdx.x*64 + w*16 + lane] = 1.f / (1.f + expf(-x));
  }
}

extern "C" void kernel_launch(void* const* d_in, const int* in_sizes, int n_in,
                              void* d_out, int out_size, void* d_ws, size_t ws_size,
                              hipStream_t stream) {
  const int*   user = (const int*)  d_in[0];
  const int*   item = (const int*)  d_in[1];
  const float* Wug  = (const float*)d_in[2];
  const float* bug  = (const float*)d_in[3];
  const float* Wum  = (const float*)d_in[4];
  const float* bum  = (const float*)d_in[5];
  const float* Wig  = (const float*)d_in[6];
  const float* big  = (const float*)d_in[7];
  const float* Wim  = (const float*)d_in[8];
  const float* bim  = (const float*)d_in[9];
  const float* W1   = (const float*)d_in[10];
  const float* b1   = (const float*)d_in[11];
  const float* W2   = (const float*)d_in[12];
  const float* b2   = (const float*)d_in[13];
  const float* W3   = (const float*)d_in[14];
  const float* b3   = (const float*)d_in[15];
  const float* Wp   = (const float*)d_in[16];
  const float* bp   = (const float*)d_in[17];
  float* out = (float*)d_out;
  unsigned int* ws = (unsigned int*)d_ws;

  ncf_convert<<<52, 256, 0, stream>>>(W1, W2, W3, ws);

  (void)hipFuncSetAttribute(reinterpret_cast<const void*>(ncf_mfma),
                            hipFuncAttributeMaxDynamicSharedMemorySize, SM_BYTES);
  ncf_mfma<<<NBLK, TPB, SM_BYTES, stream>>>(
      user, item, Wug, bug, Wum, bum, Wig, big, Wim, bim,
      b1, b2, b3, Wp, bp, ws, out);
}

// Round 5
// 17.781 us; speedup vs baseline: 1.1048x; 1.1048x over previous
//
#include <hip/hip_runtime.h>
#include <math.h>

typedef __attribute__((ext_vector_type(8))) short bf16x8;
typedef __attribute__((ext_vector_type(4))) float f32x4;
typedef __attribute__((ext_vector_type(4))) unsigned int u32x4;

#define TPB  256
#define NBLK 256

// LDS byte offsets
#define W1T_OFF 0                       // [128 n][272 B]  (136 bf16 k-slots)
#define W2T_OFF 34816                   // [64  n][272 B]
#define W3T_OFF 52224                   // [32  n][144 B]
#define SCR_OFF 56832                   // per-wave [16][272 B] scratch
#define SCR_PW  4352
#define SM_BYTES 74240

__device__ __forceinline__ unsigned short f2bf(float a){
  unsigned ua = __float_as_uint(a);
  return (unsigned short)((ua + 0x7FFFu + ((ua>>16)&1u)) >> 16);   // RNE
}
__device__ __forceinline__ unsigned int f2bf_pk(float a, float b){
  return (unsigned int)f2bf(a) | ((unsigned int)f2bf(b) << 16);
}
__device__ __forceinline__ bf16x8 mk_frag(float4 a, float4 ba, float4 b, float4 bb){
  union { bf16x8 v; unsigned int u[4]; } o;
  o.u[0] = f2bf_pk(fmaxf(a.x+ba.x,0.f), fmaxf(a.y+ba.y,0.f));
  o.u[1] = f2bf_pk(fmaxf(a.z+ba.z,0.f), fmaxf(a.w+ba.w,0.f));
  o.u[2] = f2bf_pk(fmaxf(b.x+bb.x,0.f), fmaxf(b.y+bb.y,0.f));
  o.u[3] = f2bf_pk(fmaxf(b.z+bb.z,0.f), fmaxf(b.w+bb.w,0.f));
  return o.v;
}

__launch_bounds__(TPB, 2)
__global__ void ncf_mfma(
    const int* __restrict__ user, const int* __restrict__ item,
    const float* __restrict__ Wug, const float* __restrict__ bug,
    const float* __restrict__ Wum, const float* __restrict__ bum,
    const float* __restrict__ Wig, const float* __restrict__ big,
    const float* __restrict__ Wim, const float* __restrict__ bim,
    const float* __restrict__ W1, const float* __restrict__ b1,
    const float* __restrict__ W2, const float* __restrict__ b2,
    const float* __restrict__ W3, const float* __restrict__ b3,
    const float* __restrict__ Wp, const float* __restrict__ bp,
    float* __restrict__ out)
{
  extern __shared__ __align__(16) char sm[];
  const int t    = threadIdx.x;
  const int lane = t & 63;
  const int w    = t >> 6;           // 0..3
  const int r    = lane & 15;
  const int g    = lane >> 4;
  const int gb   = blockIdx.x * 64 + w * 16 + r;

  // ---- issue index + embedding gathers first (longest latency) ----
  const int u  = user[gb];
  const int it = item[gb];
  const float* up = Wum + (size_t)u  * 64;
  const float* ip = Wim + (size_t)it * 64;
  float4 mu0 = *(const float4*)(up + 8*g);
  float4 mu1 = *(const float4*)(up + 8*g + 4);
  float4 mu2 = *(const float4*)(up + 32 + 8*g);
  float4 mu3 = *(const float4*)(up + 32 + 8*g + 4);
  float4 mi0 = *(const float4*)(ip + 8*g);
  float4 mi1 = *(const float4*)(ip + 8*g + 4);
  float4 mi2 = *(const float4*)(ip + 32 + 8*g);
  float4 mi3 = *(const float4*)(ip + 32 + 8*g + 4);

  const float* ugp = Wug + (size_t)u  * 64 + 16*g;
  const float* igp = Wig + (size_t)it * 64 + 16*g;

  // ---- staging: column-wise loads -> pack -> conflict-free b128 writes ----
  // Task (n, kb): 8 coalesced dword loads down col n (k = 8kb..8kb+7),
  // pack 4 k-pair words, single ds_write_b128 at [n][kb*16B].
  // Bank check: word base = 68n + 4kb; 4n mod 32 -> every 8 consecutive n
  // span all 32 banks exactly once for a b128 -> minimum 8-cycle wave write.
  #pragma unroll
  for (int i = 0; i < 8; ++i) {                  // W1: 128n x 16kb = 2048 tasks
    int tau = i*TPB + t; int n = tau & 127, kb = tau >> 7;
    const float* src = W1 + (size_t)(8*kb)*128 + n;
    u32x4 v = { f2bf_pk(src[0],   src[128]),
                f2bf_pk(src[256], src[384]),
                f2bf_pk(src[512], src[640]),
                f2bf_pk(src[768], src[896]) };
    *(u32x4*)(sm + W1T_OFF + n*272 + kb*16) = v;
  }
  #pragma unroll
  for (int i = 0; i < 4; ++i) {                  // W2: 64n x 16kb = 1024 tasks
    int tau = i*TPB + t; int n = tau & 63, kb = tau >> 6;
    const float* src = W2 + (size_t)(8*kb)*64 + n;
    u32x4 v = { f2bf_pk(src[0],   src[64]),
                f2bf_pk(src[128], src[192]),
                f2bf_pk(src[256], src[320]),
                f2bf_pk(src[384], src[448]) };
    *(u32x4*)(sm + W2T_OFF + n*272 + kb*16) = v;
  }
  {                                              // W3: 32n x 8kb = 256 tasks
    int n = t & 31, kb = t >> 5;
    const float* src = W3 + (size_t)(8*kb)*32 + n;
    u32x4 v = { f2bf_pk(src[0],   src[32]),
                f2bf_pk(src[64],  src[96]),
                f2bf_pk(src[128], src[160]),
                f2bf_pk(src[192], src[224]) };
    *(u32x4*)(sm + W3T_OFF + n*144 + kb*16) = v;
  }

  // ---- GMF (f32 exact): this lane's 16 cols ----
  float psum = 0.f;
  #pragma unroll
  for (int c = 0; c < 4; ++c) {
    float4 ga  = *(const float4*)(ugp + 4*c);
    float4 gi  = *(const float4*)(igp + 4*c);
    float4 gba = *(const float4*)(bug + 16*g + 4*c);
    float4 gbb = *(const float4*)(big + 16*g + 4*c);
    float4 wpv = *(const float4*)(Wp  + 16*g + 4*c);
    psum += fmaxf(ga.x+gba.x,0.f) * fmaxf(gi.x+gbb.x,0.f) * wpv.x;
    psum += fmaxf(ga.y+gba.y,0.f) * fmaxf(gi.y+gbb.y,0.f) * wpv.y;
    psum += fmaxf(ga.z+gba.z,0.f) * fmaxf(gi.z+gbb.z,0.f) * wpv.z;
    psum += fmaxf(ga.w+gba.w,0.f) * fmaxf(gi.w+gbb.w,0.f) * wpv.w;
  }

  // ---- layer-1 A fragments straight from the gather ----
  float4 bu0 = *(const float4*)(bum + 8*g);      float4 bu1 = *(const float4*)(bum + 8*g + 4);
  float4 bu2 = *(const float4*)(bum + 32 + 8*g); float4 bu3 = *(const float4*)(bum + 32 + 8*g + 4);
  float4 bi0 = *(const float4*)(bim + 8*g);      float4 bi1 = *(const float4*)(bim + 8*g + 4);
  float4 bi2 = *(const float4*)(bim + 32 + 8*g); float4 bi3 = *(const float4*)(bim + 32 + 8*g + 4);
  bf16x8 afr[4];
  afr[0] = mk_frag(mu0, bu0, mu1, bu1);
  afr[1] = mk_frag(mu2, bu2, mu3, bu3);
  afr[2] = mk_frag(mi0, bi0, mi1, bi1);
  afr[3] = mk_frag(mi2, bi2, mi3, bi3);

  float b1v[8], b2v[4], b3v[2], wp3[2];
  #pragma unroll
  for (int i = 0; i < 8; ++i) b1v[i] = b1[i*16 + r];
  #pragma unroll
  for (int i = 0; i < 4; ++i) b2v[i] = b2[i*16 + r];
  #pragma unroll
  for (int i = 0; i < 2; ++i) { b3v[i] = b3[i*16 + r]; wp3[i] = Wp[64 + i*16 + r]; }
  const float bpv = bp[0];

  __syncthreads();   // weights staged

  char* scr = sm + SCR_OFF + w * SCR_PW;   // wave-private scratch

  // ---- layer 1: [16,128] @ [128,128] ----
  #pragma unroll
  for (int nt = 0; nt < 8; ++nt) {
    f32x4 acc = {b1v[nt], b1v[nt], b1v[nt], b1v[nt]};
    #pragma unroll
    for (int s = 0; s < 4; ++s) {
      bf16x8 bf = *(const bf16x8*)(sm + W1T_OFF + (nt*16 + r)*272 + s*64 + g*16);
      acc = __builtin_amdgcn_mfma_f32_16x16x32_bf16(afr[s], bf, acc, 0, 0, 0);
    }
    #pragma unroll
    for (int q = 0; q < 4; ++q)
      *(unsigned short*)(scr + (4*g + q)*272 + (nt*16 + r)*2) = f2bf(fmaxf(acc[q], 0.f));
  }

  // ---- layer 2: [16,128] @ [128,64] ----
  bf16x8 a2[4];
  #pragma unroll
  for (int s = 0; s < 4; ++s)
    a2[s] = *(const bf16x8*)(scr + r*272 + s*64 + g*16);
  #pragma unroll
  for (int nt = 0; nt < 4; ++nt) {
    f32x4 acc = {b2v[nt], b2v[nt], b2v[nt], b2v[nt]};
    #pragma unroll
    for (int s = 0; s < 4; ++s) {
      bf16x8 bf = *(const bf16x8*)(sm + W2T_OFF + (nt*16 + r)*272 + s*64 + g*16);
      acc = __builtin_amdgcn_mfma_f32_16x16x32_bf16(a2[s], bf, acc, 0, 0, 0);
    }
    #pragma unroll
    for (int q = 0; q < 4; ++q)
      *(unsigned short*)(scr + (4*g + q)*144 + (nt*16 + r)*2) = f2bf(fmaxf(acc[q], 0.f));
  }

  // ---- layer 3: [16,64] @ [64,32] ----
  bf16x8 a3[2];
  #pragma unroll
  for (int s = 0; s < 2; ++s)
    a3[s] = *(const bf16x8*)(scr + r*144 + s*64 + g*16);
  float h3p[4] = {0.f, 0.f, 0.f, 0.f};
  #pragma unroll
  for (int nt = 0; nt < 2; ++nt) {
    f32x4 acc = {b3v[nt], b3v[nt], b3v[nt], b3v[nt]};
    #pragma unroll
    for (int s = 0; s < 2; ++s) {
      bf16x8 bf = *(const bf16x8*)(sm + W3T_OFF + (nt*16 + r)*144 + s*64 + g*16);
      acc = __builtin_amdgcn_mfma_f32_16x16x32_bf16(a3[s], bf, acc, 0, 0, 0);
    }
    #pragma unroll
    for (int q = 0; q < 4; ++q)
      h3p[q] += fmaxf(acc[q], 0.f) * wp3[nt];
  }

  // ---- final reduce in wave-private scratch (f32 [16][20]) ----
  float* scf = (float*)scr;
  #pragma unroll
  for (int q = 0; q < 4; ++q) scf[(4*g + q)*20 + r] = h3p[q];
  scf[r*20 + 16 + g] = psum;
  __builtin_amdgcn_wave_barrier();

  if (lane < 16) {
    const float4* row = (const float4*)(scf + lane*20);
    float x = bpv;
    #pragma unroll
    for (int i = 0; i < 5; ++i) { float4 v = row[i]; x += v.x + v.y + v.z + v.w; }
    out[blockIdx.x*64 + w*16 + lane] = 1.f / (1.f + expf(-x));
  }
}

extern "C" void kernel_launch(void* const* d_in, const int* in_sizes, int n_in,
                              void* d_out, int out_size, void* d_ws, size_t ws_size,
                              hipStream_t stream) {
  const int*   user = (const int*)  d_in[0];
  const int*   item = (const int*)  d_in[1];
  const float* Wug  = (const float*)d_in[2];
  const float* bug  = (const float*)d_in[3];
  const float* Wum  = (const float*)d_in[4];
  const float* bum  = (const float*)d_in[5];
  const float* Wig  = (const float*)d_in[6];
  const float* big  = (const float*)d_in[7];
  const float* Wim  = (const float*)d_in[8];
  const float* bim  = (const float*)d_in[9];
  const float* W1   = (const float*)d_in[10];
  const float* b1   = (const float*)d_in[11];
  const float* W2   = (const float*)d_in[12];
  const float* b2   = (const float*)d_in[13];
  const float* W3   = (const float*)d_in[14];
  const float* b3   = (const float*)d_in[15];
  const float* Wp   = (const float*)d_in[16];
  const float* bp   = (const float*)d_in[17];
  float* out = (float*)d_out;

  (void)hipFuncSetAttribute(reinterpret_cast<const void*>(ncf_mfma),
                            hipFuncAttributeMaxDynamicSharedMemorySize, SM_BYTES);
  ncf_mfma<<<NBLK, TPB, SM_BYTES, stream>>>(
      user, item, Wug, bug, Wum, bum, Wig, big, Wim, bim,
      W1, b1, W2, b2, W3, b3, Wp, bp, out);
}

// Round 6
// 12.395 us; speedup vs baseline: 1.5850x; 1.4346x over previous
//
#include <hip/hip_runtime.h>
#include <math.h>

typedef __attribute__((ext_vector_type(8))) short bf16x8;
typedef __attribute__((ext_vector_type(4))) float f32x4;

#define TPB  256
#define NBLK 256

// LDS byte offsets (all 16B-aligned). Row strides 272B/144B: lanes 0-15 hit
// each bank exactly 2x on b128 reads -> 2-way conflict = free (m136).
#define W1T_OFF 0                       // [128 n][136 k] bf16, stride 272B
#define W2T_OFF 34816                   // [64  n][136 k] bf16, stride 272B
#define W3T_OFF 52224                   // [32  n][72  k] bf16, stride 144B
#define SCR_OFF 56832                   // per-wave [16][136] bf16 scratch
#define SCR_PW  4352
#define SM_BYTES (SCR_OFF + 4*SCR_PW)   // 74240 B

__device__ __forceinline__ unsigned short f2bf(float a){
  unsigned ua = __float_as_uint(a);
  return (unsigned short)((ua + 0x7FFFu + ((ua>>16)&1u)) >> 16);   // RNE
}
__device__ __forceinline__ unsigned int f2bf_pk(float a, float b){
  return (unsigned int)f2bf(a) | ((unsigned int)f2bf(b) << 16);
}
__device__ __forceinline__ bf16x8 mk_frag(float4 a, float4 ba, float4 b, float4 bb){
  union { bf16x8 v; unsigned int u[4]; } o;
  o.u[0] = f2bf_pk(fmaxf(a.x+ba.x,0.f), fmaxf(a.y+ba.y,0.f));
  o.u[1] = f2bf_pk(fmaxf(a.z+ba.z,0.f), fmaxf(a.w+ba.w,0.f));
  o.u[2] = f2bf_pk(fmaxf(b.x+bb.x,0.f), fmaxf(b.y+bb.y,0.f));
  o.u[3] = f2bf_pk(fmaxf(b.z+bb.z,0.f), fmaxf(b.w+bb.w,0.f));
  return o.v;
}

__launch_bounds__(TPB, 2)
__global__ void ncf_mfma(
    const int* __restrict__ user, const int* __restrict__ item,
    const float* __restrict__ Wug, const float* __restrict__ bug,
    const float* __restrict__ Wum, const float* __restrict__ bum,
    const float* __restrict__ Wig, const float* __restrict__ big,
    const float* __restrict__ Wim, const float* __restrict__ bim,
    const float* __restrict__ W1, const float* __restrict__ b1,
    const float* __restrict__ W2, const float* __restrict__ b2,
    const float* __restrict__ W3, const float* __restrict__ b3,
    const float* __restrict__ Wp, const float* __restrict__ bp,
    float* __restrict__ out)
{
  extern __shared__ __align__(16) char sm[];
  const int t    = threadIdx.x;
  const int lane = t & 63;
  const int w    = t >> 6;           // 0..3
  const int r    = lane & 15;
  const int g    = lane >> 4;
  const int gb   = blockIdx.x * 64 + w * 16 + r;

  // ---- 1. index loads first (longest dependent chain starts here) ----
  const int u  = user[gb];
  const int it = item[gb];

  // ---- 2. independent staging loads fill VMEM queue during idx latency ----
  #pragma unroll
  for (int i = 0; i < 32; ++i) {                 // W1: 128k x 128n
    int p = i*TPB + t; int n = p & 127, kp = p >> 7;
    float f0 = W1[(2*kp)*128 + n], f1 = W1[(2*kp+1)*128 + n];
    *(unsigned int*)(sm + W1T_OFF + n*272 + kp*4) = f2bf_pk(f0, f1);
  }
  #pragma unroll
  for (int i = 0; i < 16; ++i) {                 // W2: 128k x 64n
    int p = i*TPB + t; int n = p & 63, kp = p >> 6;
    float f0 = W2[(2*kp)*64 + n], f1 = W2[(2*kp+1)*64 + n];
    *(unsigned int*)(sm + W2T_OFF + n*272 + kp*4) = f2bf_pk(f0, f1);
  }
  #pragma unroll
  for (int i = 0; i < 4; ++i) {                  // W3: 64k x 32n
    int p = i*TPB + t; int n = p & 31, kp = p >> 5;
    float f0 = W3[(2*kp)*32 + n], f1 = W3[(2*kp+1)*32 + n];
    *(unsigned int*)(sm + W3T_OFF + n*144 + kp*4) = f2bf_pk(f0, f1);
  }

  // ---- 3. dependent embedding / GMF gathers (idx has arrived by now) ----
  const float* up = Wum + (size_t)u  * 64;
  const float* ip = Wim + (size_t)it * 64;
  float4 mu0 = *(const float4*)(up + 8*g);
  float4 mu1 = *(const float4*)(up + 8*g + 4);
  float4 mu2 = *(const float4*)(up + 32 + 8*g);
  float4 mu3 = *(const float4*)(up + 32 + 8*g + 4);
  float4 mi0 = *(const float4*)(ip + 8*g);
  float4 mi1 = *(const float4*)(ip + 8*g + 4);
  float4 mi2 = *(const float4*)(ip + 32 + 8*g);
  float4 mi3 = *(const float4*)(ip + 32 + 8*g + 4);
  float4 bu0 = *(const float4*)(bum + 8*g);
  float4 bu1 = *(const float4*)(bum + 8*g + 4);
  float4 bu2 = *(const float4*)(bum + 32 + 8*g);
  float4 bu3 = *(const float4*)(bum + 32 + 8*g + 4);
  float4 bi0 = *(const float4*)(bim + 8*g);
  float4 bi1 = *(const float4*)(bim + 8*g + 4);
  float4 bi2 = *(const float4*)(bim + 32 + 8*g);
  float4 bi3 = *(const float4*)(bim + 32 + 8*g + 4);

  const float* ugp = Wug + (size_t)u  * 64 + 16*g;
  const float* igp = Wig + (size_t)it * 64 + 16*g;
  float psum = 0.f;
  #pragma unroll
  for (int c = 0; c < 4; ++c) {
    float4 ga  = *(const float4*)(ugp + 4*c);
    float4 gi  = *(const float4*)(igp + 4*c);
    float4 gba = *(const float4*)(bug + 16*g + 4*c);
    float4 gbb = *(const float4*)(big + 16*g + 4*c);
    float4 wpv = *(const float4*)(Wp  + 16*g + 4*c);
    psum += fmaxf(ga.x+gba.x,0.f) * fmaxf(gi.x+gbb.x,0.f) * wpv.x;
    psum += fmaxf(ga.y+gba.y,0.f) * fmaxf(gi.y+gbb.y,0.f) * wpv.y;
    psum += fmaxf(ga.z+gba.z,0.f) * fmaxf(gi.z+gbb.z,0.f) * wpv.z;
    psum += fmaxf(ga.w+gba.w,0.f) * fmaxf(gi.w+gbb.w,0.f) * wpv.w;
  }

  // ---- layer-1 A fragments straight from the gather ----
  bf16x8 afr[4];
  afr[0] = mk_frag(mu0, bu0, mu1, bu1);
  afr[1] = mk_frag(mu2, bu2, mu3, bu3);
  afr[2] = mk_frag(mi0, bi0, mi1, bi1);
  afr[3] = mk_frag(mi2, bi2, mi3, bi3);

  float b1v[8], b2v[4], b3v[2], wp3[2];
  #pragma unroll
  for (int i = 0; i < 8; ++i) b1v[i] = b1[i*16 + r];
  #pragma unroll
  for (int i = 0; i < 4; ++i) b2v[i] = b2[i*16 + r];
  #pragma unroll
  for (int i = 0; i < 2; ++i) { b3v[i] = b3[i*16 + r]; wp3[i] = Wp[64 + i*16 + r]; }
  const float bpv = bp[0];

  __syncthreads();   // weights staged; the only block-wide barrier

  char* scr = sm + SCR_OFF + w * SCR_PW;   // wave-private scratch

  // ---- layer 1: [16,128] @ [128,128] ----
  #pragma unroll
  for (int nt = 0; nt < 8; ++nt) {
    f32x4 acc = {b1v[nt], b1v[nt], b1v[nt], b1v[nt]};
    #pragma unroll
    for (int s = 0; s < 4; ++s) {
      bf16x8 bf = *(const bf16x8*)(sm + W1T_OFF + (nt*16 + r)*272 + s*64 + g*16);
      acc = __builtin_amdgcn_mfma_f32_16x16x32_bf16(afr[s], bf, acc, 0, 0, 0);
    }
    #pragma unroll
    for (int q = 0; q < 4; ++q)   // D: col = nt*16+r, rows = 4g+q
      *(unsigned short*)(scr + (4*g + q)*272 + (nt*16 + r)*2) = f2bf(fmaxf(acc[q], 0.f));
  }

  // ---- layer 2: [16,128] @ [128,64] ----
  bf16x8 a2[4];
  #pragma unroll
  for (int s = 0; s < 4; ++s)
    a2[s] = *(const bf16x8*)(scr + r*272 + s*64 + g*16);
  #pragma unroll
  for (int nt = 0; nt < 4; ++nt) {
    f32x4 acc = {b2v[nt], b2v[nt], b2v[nt], b2v[nt]};
    #pragma unroll
    for (int s = 0; s < 4; ++s) {
      bf16x8 bf = *(const bf16x8*)(sm + W2T_OFF + (nt*16 + r)*272 + s*64 + g*16);
      acc = __builtin_amdgcn_mfma_f32_16x16x32_bf16(a2[s], bf, acc, 0, 0, 0);
    }
    #pragma unroll
    for (int q = 0; q < 4; ++q)   // H2 layout [16][72] bf16 in same scratch
      *(unsigned short*)(scr + (4*g + q)*144 + (nt*16 + r)*2) = f2bf(fmaxf(acc[q], 0.f));
  }

  // ---- layer 3: [16,64] @ [64,32], keep result in f32 regs ----
  bf16x8 a3[2];
  #pragma unroll
  for (int s = 0; s < 2; ++s)
    a3[s] = *(const bf16x8*)(scr + r*144 + s*64 + g*16);
  float h3p[4] = {0.f, 0.f, 0.f, 0.f};
  #pragma unroll
  for (int nt = 0; nt < 2; ++nt) {
    f32x4 acc = {b3v[nt], b3v[nt], b3v[nt], b3v[nt]};
    #pragma unroll
    for (int s = 0; s < 2; ++s) {
      bf16x8 bf = *(const bf16x8*)(sm + W3T_OFF + (nt*16 + r)*144 + s*64 + g*16);
      acc = __builtin_amdgcn_mfma_f32_16x16x32_bf16(a3[s], bf, acc, 0, 0, 0);
    }
    #pragma unroll
    for (int q = 0; q < 4; ++q)
      h3p[q] += fmaxf(acc[q], 0.f) * wp3[nt];   // * Wp[64 + nt*16 + r]
  }

  // ---- final reduce in wave-private scratch (f32 [16][20]) ----
  float* scf = (float*)scr;
  #pragma unroll
  for (int q = 0; q < 4; ++q) scf[(4*g + q)*20 + r] = h3p[q];  // h3 col-partials
  scf[r*20 + 16 + g] = psum;                                   // gmf g-partials
  __builtin_amdgcn_wave_barrier();  // ordering hint only; same-wave lgkmcnt applies

  if (lane < 16) {
    float x = bpv;
    const float4* row = (const float4*)(scf + lane*20);
    #pragma unroll
    for (int i = 0; i < 5; ++i) { float4 v = row[i]; x += v.x + v.y + v.z + v.w; }
    out[blockIdx.x*64 + w*16 + lane] = 1.f / (1.f + expf(-x));
  }
}

extern "C" void kernel_launch(void* const* d_in, const int* in_sizes, int n_in,
                              void* d_out, int out_size, void* d_ws, size_t ws_size,
                              hipStream_t stream) {
  const int*   user = (const int*)  d_in[0];
  const int*   item = (const int*)  d_in[1];
  const float* Wug  = (const float*)d_in[2];
  const float* bug  = (const float*)d_in[3];
  const float* Wum  = (const float*)d_in[4];
  const float* bum  = (const float*)d_in[5];
  const float* Wig  = (const float*)d_in[6];
  const float* big  = (const float*)d_in[7];
  const float* Wim  = (const float*)d_in[8];
  const float* bim  = (const float*)d_in[9];
  const float* W1   = (const float*)d_in[10];
  const float* b1   = (const float*)d_in[11];
  const float* W2   = (const float*)d_in[12];
  const float* b2   = (const float*)d_in[13];
  const float* W3   = (const float*)d_in[14];
  const float* b3   = (const float*)d_in[15];
  const float* Wp   = (const float*)d_in[16];
  const float* bp   = (const float*)d_in[17];
  float* out = (float*)d_out;

  (void)hipFuncSetAttribute(reinterpret_cast<const void*>(ncf_mfma),
                            hipFuncAttributeMaxDynamicSharedMemorySize, SM_BYTES);
  ncf_mfma<<<NBLK, TPB, SM_BYTES, stream>>>(
      user, item, Wug, bug, Wum, bum, Wig, big, Wim, bim,
      W1, b1, W2, b2, W3, b3, Wp, bp, out);
}